// Round 1
// baseline (404.070 us; speedup 1.0000x reference)
//
#include <hip/hip_runtime.h>

// ---------------------------------------------------------------------------
// GPT-2 attention block on MI355X (gfx950), bf16-MFMA pipeline, fp32 I/O.
//   S=2048 queries, P=2048 past, T=4096 total keys, E=1024, H=16, D=64.
// Stages:
//   1. convert x -> bf16                       (k_cvt_x)
//   2. transpose+convert c_attn_w -> [3E][E]   (k_tr_cvt)
//   3. transpose+convert c_proj_w -> [E][E]    (k_tr_cvt)
//   4. past_key  -> present[0] fp32 + Kb bf16  (k_past_key)
//   5. past_value-> present[1] fp32 + Vt bf16  (k_past_value, transposed)
//   6. QKV GEMM (bf16 MFMA, 128x128 tile), epilogue scatters q/k/v
//   7. flash attention (swapped QK^T, online softmax)   (k_attn)
//   8. proj GEMM -> d_out a                    (k_gemm<1>)
// ---------------------------------------------------------------------------

#define SDIM 2048
#define PDIM 2048
#define TDIM 4096
#define EDIM 1024
#define HNUM 16
#define DDIM 64

typedef short bf16x8 __attribute__((ext_vector_type(8)));   // 8 bf16 (4 VGPRs)
typedef float f32x4 __attribute__((ext_vector_type(4)));
typedef unsigned int u32x2 __attribute__((ext_vector_type(2)));

__device__ __forceinline__ unsigned short f2bf(float f) {
    union { float f; unsigned u; } v; v.f = f;
    unsigned r = v.u + 0x7fffu + ((v.u >> 16) & 1u);        // RNE
    return (unsigned short)(r >> 16);
}

__device__ __forceinline__ void async16(const void* g, void* l) {
    __builtin_amdgcn_global_load_lds(
        (const __attribute__((address_space(1))) void*)g,
        (__attribute__((address_space(3))) void*)l, 16, 0, 0);
}

// --------------------------- prep kernels ----------------------------------

__global__ __launch_bounds__(256) void k_cvt_x(const float* __restrict__ in,
                                               short* __restrict__ out) {
    int i = (blockIdx.x * 256 + threadIdx.x) * 4;
    f32x4 v = *(const f32x4*)(in + i);
    unsigned lo = f2bf(v[0]) | ((unsigned)f2bf(v[1]) << 16);
    unsigned hi = f2bf(v[2]) | ((unsigned)f2bf(v[3]) << 16);
    u32x2 p = {lo, hi};
    *(u32x2*)(out + i) = p;
}

// in [R][C] fp32 -> out [C][R] bf16
__global__ __launch_bounds__(256) void k_tr_cvt(const float* __restrict__ in,
                                                short* __restrict__ out,
                                                int R, int C) {
    __shared__ float tile[32][33];
    int cb = blockIdx.x * 32, rb = blockIdx.y * 32;
    int c = threadIdx.x & 31, r0 = threadIdx.x >> 5;
#pragma unroll
    for (int i = 0; i < 4; ++i)
        tile[r0 + 8 * i][c] = in[(rb + r0 + 8 * i) * C + cb + c];
    __syncthreads();
#pragma unroll
    for (int i = 0; i < 4; ++i)
        out[(cb + r0 + 8 * i) * R + rb + c] = (short)f2bf(tile[c][r0 + 8 * i]);
}

// past_key [H][P][D] -> present_k fp32 [H][T][D] (t<P) + Kb bf16 same layout
__global__ __launch_bounds__(256) void k_past_key(const float* __restrict__ pk,
                                                  short* __restrict__ Kb,
                                                  float* __restrict__ pk_out) {
    int i = (blockIdx.x * 256 + threadIdx.x) * 4;   // over H*P*D = 2M
    int h = i >> 17;                                // P*D = 131072
    f32x4 v = *(const f32x4*)(pk + i);
    int dst = i + (h << 17);                        // [H][T][D], first half
    *(f32x4*)(pk_out + dst) = v;
    unsigned lo = f2bf(v[0]) | ((unsigned)f2bf(v[1]) << 16);
    unsigned hi = f2bf(v[2]) | ((unsigned)f2bf(v[3]) << 16);
    u32x2 p = {lo, hi};
    *(u32x2*)(Kb + dst) = p;
}

// past_value [H][P][D] -> present_v fp32 + Vt bf16 [H][D][T] (transposed)
__global__ __launch_bounds__(256) void k_past_value(const float* __restrict__ pv,
                                                    short* __restrict__ Vt,
                                                    float* __restrict__ pv_out) {
    __shared__ float tile[32][33];
    int h = blockIdx.z;
    int tb = blockIdx.x * 32;   // t
    int db = blockIdx.y * 32;   // d
    int c = threadIdx.x & 31, r0 = threadIdx.x >> 5;
    const float* src = pv + (h << 17);
    float* dst = pv_out + (h << 18);
#pragma unroll
    for (int i = 0; i < 4; ++i) {
        int r = r0 + 8 * i;
        float v = src[(tb + r) * DDIM + db + c];
        tile[r][c] = v;
        dst[(tb + r) * DDIM + db + c] = v;
    }
    __syncthreads();
#pragma unroll
    for (int i = 0; i < 4; ++i) {
        int d = r0 + 8 * i;
        Vt[(h * DDIM + db + d) * TDIM + tb + c] = (short)f2bf(tile[c][d]);
    }
}

// --------------------------- GEMM (m97 structure) --------------------------
// A [M][K] bf16, Bt [N][K] bf16 (pre-transposed). 128x128 tile, BK=32,
// 256 thr = 4 waves (2x2 of 64x64), 16x16x32 MFMA.
// MODE 0: QKV epilogue (q_ws/Kb/Vt/present). MODE 1: proj -> fp32 out + bias.

template <int MODE>
__global__ __launch_bounds__(256) void k_gemm(
    const short* __restrict__ A, const short* __restrict__ Bt,
    const float* __restrict__ bias, int K,
    short* __restrict__ q_ws, short* __restrict__ Kb, short* __restrict__ Vt,
    float* __restrict__ pk, float* __restrict__ pv,
    float* __restrict__ outF, int N) {
    __shared__ short As[128 * 32];
    __shared__ short Bs[128 * 32];
    const int tid = threadIdx.x;
    const int m0 = blockIdx.y * 128, n0 = blockIdx.x * 128;
    const int w = tid >> 6, lane = tid & 63;
    const int wm = w >> 1, wn = w & 1;
    const int l15 = lane & 15, g = lane >> 4;

    f32x4 zero = {0.f, 0.f, 0.f, 0.f};
    f32x4 acc[4][4];
#pragma unroll
    for (int i = 0; i < 4; ++i)
#pragma unroll
        for (int j = 0; j < 4; ++j) acc[i][j] = zero;

    const int arow = tid >> 2;
    const int acol = (tid & 3) << 3;
    const short* Ab  = A  + (m0 + arow) * K + acol;
    const short* Ab2 = A  + (m0 + 64 + arow) * K + acol;
    const short* Bb  = Bt + (n0 + arow) * K + acol;
    const short* Bb2 = Bt + (n0 + 64 + arow) * K + acol;
    short* lA  = &As[tid * 8];
    short* lA2 = &As[2048 + tid * 8];
    short* lB  = &Bs[tid * 8];
    short* lB2 = &Bs[2048 + tid * 8];

    const int aoff = (wm * 64 + l15) * 32 + g * 8;
    const int boff = (wn * 64 + l15) * 32 + g * 8;

    for (int kt = 0; kt < K; kt += 32) {
        async16(Ab + kt, lA);
        async16(Ab2 + kt, lA2);
        async16(Bb + kt, lB);
        async16(Bb2 + kt, lB2);
        __syncthreads();                    // drains vmcnt before use
        bf16x8 af[4], bfr[4];
#pragma unroll
        for (int f = 0; f < 4; ++f) af[f]  = *(const bf16x8*)&As[aoff + f * 512];
#pragma unroll
        for (int f = 0; f < 4; ++f) bfr[f] = *(const bf16x8*)&Bs[boff + f * 512];
#pragma unroll
        for (int i = 0; i < 4; ++i)
#pragma unroll
            for (int j = 0; j < 4; ++j)
                acc[i][j] = __builtin_amdgcn_mfma_f32_16x16x32_bf16(
                    af[i], bfr[j], acc[i][j], 0, 0, 0);
        __syncthreads();
    }

    // Epilogue: C[row][col], row = m0+wm*64+i*16+4g+r, col = n0+wn*64+j*16+l15
    if (MODE == 1) {
#pragma unroll
        for (int j = 0; j < 4; ++j) {
            int ncol = n0 + wn * 64 + j * 16 + l15;
            float b = bias[ncol];
#pragma unroll
            for (int i = 0; i < 4; ++i) {
                int mb = m0 + wm * 64 + i * 16 + g * 4;
#pragma unroll
                for (int r = 0; r < 4; ++r)
                    outF[(mb + r) * N + ncol] = acc[i][j][r] + b;
            }
        }
    } else {
        const int sec = n0 >> 10;   // 0=q 1=k 2=v (uniform per block)
#pragma unroll
        for (int j = 0; j < 4; ++j) {
            int ncol = n0 + wn * 64 + j * 16 + l15;
            float b = bias[ncol];
            int h = (ncol >> 6) & 15;
            int d = ncol & 63;
#pragma unroll
            for (int i = 0; i < 4; ++i) {
                int mb = m0 + wm * 64 + i * 16 + g * 4;
#pragma unroll
                for (int r = 0; r < 4; ++r) {
                    int s = mb + r;
                    float val = acc[i][j][r] + b;
                    if (sec == 0) {
                        q_ws[(h * SDIM + s) * DDIM + d] = (short)f2bf(val * 0.125f);
                    } else if (sec == 1) {
                        int idx = (h * TDIM + PDIM + s) * DDIM + d;
                        pk[idx] = val;
                        Kb[idx] = (short)f2bf(val);
                    } else {
                        pv[(h * TDIM + PDIM + s) * DDIM + d] = val;
                        Vt[(h * DDIM + d) * TDIM + PDIM + s] = (short)f2bf(val);
                    }
                }
            }
        }
    }
}

// --------------------------- flash attention -------------------------------
// Block: head h = bid%16 (XCD-groups a head's KV), q-tile qt = bid/16.
// 4 waves x 16 q-rows. Swapped QK^T: S^T = mfma(A=K, B=Q) so each lane owns
// one q-row (col = lane&15): softmax stats are 2 shfl_xor away. P goes
// through a 144B-stride LDS buffer to become the PV B-operand (O^T = Vt.P^T).
__global__ __launch_bounds__(256) void k_attn(const short* __restrict__ q_ws,
                                              const short* __restrict__ Kb,
                                              const short* __restrict__ Vt,
                                              short* __restrict__ aout) {
    __shared__ short Pl[4][16][72];   // per wave: [q 16][key 64], +8 pad
    const int tid = threadIdx.x;
    const int w = tid >> 6, lane = tid & 63;
    const int l15 = lane & 15, g = lane >> 4;
    const int h = blockIdx.x & 15;
    const int qt = blockIdx.x >> 4;
    const int q = qt * 64 + w * 16 + l15;   // this lane's q row

    const short* qb = q_ws + (h * SDIM + q) * DDIM;   // pre-scaled by 0.125
    bf16x8 bq0 = *(const bf16x8*)(qb + g * 8);
    bf16x8 bq1 = *(const bf16x8*)(qb + 32 + g * 8);

    const short* Kh = Kb + h * TDIM * DDIM;
    const short* Vh = Vt + h * DDIM * TDIM;

    f32x4 zero = {0.f, 0.f, 0.f, 0.f};
    f32x4 o[4] = {zero, zero, zero, zero};
    float m_run = -1e30f, l_run = 0.f;
    const int ntiles = 33 + qt;             // exactly covers keys <= P+q0+63
    short* myP = &Pl[w][0][0];

    for (int t = 0; t < ntiles; ++t) {
        const int t0 = t * 64;
        f32x4 sc[4];
#pragma unroll
        for (int kb = 0; kb < 4; ++kb) {    // S^T[key][q]
            const short* krow = Kh + (t0 + kb * 16 + l15) * DDIM;
            bf16x8 ak0 = *(const bf16x8*)(krow + g * 8);
            bf16x8 ak1 = *(const bf16x8*)(krow + 32 + g * 8);
            f32x4 c = zero;
            c = __builtin_amdgcn_mfma_f32_16x16x32_bf16(ak0, bq0, c, 0, 0, 0);
            c = __builtin_amdgcn_mfma_f32_16x16x32_bf16(ak1, bq1, c, 0, 0, 0);
            sc[kb] = c;
        }
        if (t == ntiles - 1) {              // causal mask, last tile only
#pragma unroll
            for (int kb = 0; kb < 4; ++kb)
#pragma unroll
                for (int i = 0; i < 4; ++i)
                    if (t0 + kb * 16 + g * 4 + i > PDIM + q) sc[kb][i] = -1e30f;
        }
        float tmax = sc[0][0];
#pragma unroll
        for (int kb = 0; kb < 4; ++kb)
#pragma unroll
            for (int i = 0; i < 4; ++i) tmax = fmaxf(tmax, sc[kb][i]);
        tmax = fmaxf(tmax, __shfl_xor(tmax, 16));
        tmax = fmaxf(tmax, __shfl_xor(tmax, 32));
        float m_new = fmaxf(m_run, tmax);
        float scale = __expf(m_run - m_new);
        float psum = 0.f;
        unsigned pw[8];
#pragma unroll
        for (int kb = 0; kb < 4; ++kb) {
            float p0 = __expf(sc[kb][0] - m_new);
            float p1 = __expf(sc[kb][1] - m_new);
            float p2 = __expf(sc[kb][2] - m_new);
            float p3 = __expf(sc[kb][3] - m_new);
            psum += (p0 + p1) + (p2 + p3);
            pw[2 * kb]     = f2bf(p0) | ((unsigned)f2bf(p1) << 16);
            pw[2 * kb + 1] = f2bf(p2) | ((unsigned)f2bf(p3) << 16);
        }
        psum += __shfl_xor(psum, 16);
        psum += __shfl_xor(psum, 32);
        l_run = l_run * scale + psum;
        m_run = m_new;
#pragma unroll
        for (int d = 0; d < 4; ++d) o[d] *= scale;
#pragma unroll
        for (int kb = 0; kb < 4; ++kb) {    // P[q][key], 8B per lane per kb
            u32x2 pk2 = {pw[2 * kb], pw[2 * kb + 1]};
            *(u32x2*)(myP + l15 * 72 + kb * 16 + g * 4) = pk2;
        }
        asm volatile("s_waitcnt lgkmcnt(0)" ::: "memory");
        __builtin_amdgcn_sched_barrier(0);
        bf16x8 bp0 = *(const bf16x8*)(myP + l15 * 72 + g * 8);
        bf16x8 bp1 = *(const bf16x8*)(myP + l15 * 72 + 32 + g * 8);
#pragma unroll
        for (int d = 0; d < 4; ++d) {       // O^T[d][q] += V^T . P^T
            const short* vrow = Vh + (d * 16 + l15) * TDIM + t0;
            bf16x8 av0 = *(const bf16x8*)(vrow + g * 8);
            bf16x8 av1 = *(const bf16x8*)(vrow + 32 + g * 8);
            o[d] = __builtin_amdgcn_mfma_f32_16x16x32_bf16(av0, bp0, o[d], 0, 0, 0);
            o[d] = __builtin_amdgcn_mfma_f32_16x16x32_bf16(av1, bp1, o[d], 0, 0, 0);
        }
    }
    float inv = 1.0f / l_run;
#pragma unroll
    for (int d = 0; d < 4; ++d) {
        unsigned lo = f2bf(o[d][0] * inv) | ((unsigned)f2bf(o[d][1] * inv) << 16);
        unsigned hi = f2bf(o[d][2] * inv) | ((unsigned)f2bf(o[d][3] * inv) << 16);
        u32x2 pk2 = {lo, hi};
        *(u32x2*)(aout + q * EDIM + h * DDIM + d * 16 + g * 4) = pk2;
    }
}

// --------------------------- launch ----------------------------------------

extern "C" void kernel_launch(void* const* d_in, const int* in_sizes, int n_in,
                              void* d_out, int out_size, void* d_ws, size_t ws_size,
                              hipStream_t stream) {
    const float* x          = (const float*)d_in[0];
    const float* past_key   = (const float*)d_in[1];
    const float* past_value = (const float*)d_in[2];
    // d_in[3] = mask: recomputed analytically (k <= q + P)
    const float* c_attn_w   = (const float*)d_in[4];
    const float* c_attn_b   = (const float*)d_in[5];
    const float* c_proj_w   = (const float*)d_in[6];
    const float* c_proj_b   = (const float*)d_in[7];

    float* out_a  = (float*)d_out;
    float* pk_out = out_a + (size_t)SDIM * EDIM;           // present[0]
    float* pv_out = pk_out + (size_t)HNUM * TDIM * DDIM;   // present[1]

    char* ws = (char*)d_ws;
    short* xb     = (short*)(ws);                //  4 MB, reused as aout later
    short* wqkvt  = (short*)(ws + (4u  << 20));  //  6 MB  [3E][E]
    short* wprojt = (short*)(ws + (10u << 20));  //  2 MB  [E][E]
    short* q_ws   = (short*)(ws + (12u << 20));  //  4 MB  [H][S][D] *0.125
    short* Kb     = (short*)(ws + (16u << 20));  //  8 MB  [H][T][D]
    short* Vt     = (short*)(ws + (24u << 20));  //  8 MB  [H][D][T]
    short* aout   = (short*)(ws + (32u << 20));  //  4 MB  [S][E]

    k_cvt_x<<<2048, 256, 0, stream>>>(x, xb);
    k_tr_cvt<<<dim3(96, 32), 256, 0, stream>>>(c_attn_w, wqkvt, EDIM, 3 * EDIM);
    k_tr_cvt<<<dim3(32, 32), 256, 0, stream>>>(c_proj_w, wprojt, EDIM, EDIM);
    k_past_key<<<2048, 256, 0, stream>>>(past_key, Kb, pk_out);
    k_past_value<<<dim3(64, 2, 16), 256, 0, stream>>>(past_value, Vt, pv_out);

    k_gemm<0><<<dim3(24, 16), 256, 0, stream>>>(
        xb, wqkvt, c_attn_b, EDIM, q_ws, Kb, Vt, pk_out, pv_out,
        (float*)nullptr, 3 * EDIM);

    k_attn<<<512, 256, 0, stream>>>(q_ws, Kb, Vt, aout);

    k_gemm<1><<<dim3(8, 16), 256, 0, stream>>>(
        aout, wprojt, c_proj_b, EDIM,
        (short*)nullptr, (short*)nullptr, (short*)nullptr,
        (float*)nullptr, (float*)nullptr, out_a, EDIM);
}

// Round 3
// 265.647 us; speedup vs baseline: 1.5211x; 1.5211x over previous
//
#include <hip/hip_runtime.h>

// ---------------------------------------------------------------------------
// GPT-2 attention block on MI355X (gfx950), bf16-MFMA pipeline, fp32 I/O.
//   S=2048 queries, P=2048 past, T=4096 total keys, E=1024, H=16, D=64.
// R1/R2: k_attn rebuilt — LDS-staged K/V (global_load_lds w16, XOR-swizzled
//     via pre-swizzled source), double-buffered 2-phase pipeline, cvt_pk
//     P-pack, balanced qt remap. (R2 = resubmit; R1 bench never ran.)
// ---------------------------------------------------------------------------

#define SDIM 2048
#define PDIM 2048
#define TDIM 4096
#define EDIM 1024
#define HNUM 16
#define DDIM 64

typedef short bf16x8 __attribute__((ext_vector_type(8)));   // 8 bf16 (4 VGPRs)
typedef float f32x4 __attribute__((ext_vector_type(4)));
typedef unsigned int u32x2 __attribute__((ext_vector_type(2)));

__device__ __forceinline__ unsigned short f2bf(float f) {
    union { float f; unsigned u; } v; v.f = f;
    unsigned r = v.u + 0x7fffu + ((v.u >> 16) & 1u);        // RNE
    return (unsigned short)(r >> 16);
}

__device__ __forceinline__ void async16(const void* g, void* l) {
    __builtin_amdgcn_global_load_lds(
        (const __attribute__((address_space(1))) void*)g,
        (__attribute__((address_space(3))) void*)l, 16, 0, 0);
}

// --------------------------- prep kernels ----------------------------------

__global__ __launch_bounds__(256) void k_cvt_x(const float* __restrict__ in,
                                               short* __restrict__ out) {
    int i = (blockIdx.x * 256 + threadIdx.x) * 4;
    f32x4 v = *(const f32x4*)(in + i);
    unsigned lo = f2bf(v[0]) | ((unsigned)f2bf(v[1]) << 16);
    unsigned hi = f2bf(v[2]) | ((unsigned)f2bf(v[3]) << 16);
    u32x2 p = {lo, hi};
    *(u32x2*)(out + i) = p;
}

// in [R][C] fp32 -> out [C][R] bf16
__global__ __launch_bounds__(256) void k_tr_cvt(const float* __restrict__ in,
                                                short* __restrict__ out,
                                                int R, int C) {
    __shared__ float tile[32][33];
    int cb = blockIdx.x * 32, rb = blockIdx.y * 32;
    int c = threadIdx.x & 31, r0 = threadIdx.x >> 5;
#pragma unroll
    for (int i = 0; i < 4; ++i)
        tile[r0 + 8 * i][c] = in[(rb + r0 + 8 * i) * C + cb + c];
    __syncthreads();
#pragma unroll
    for (int i = 0; i < 4; ++i)
        out[(cb + r0 + 8 * i) * R + rb + c] = (short)f2bf(tile[c][r0 + 8 * i]);
}

// past_key [H][P][D] -> present_k fp32 [H][T][D] (t<P) + Kb bf16 same layout
__global__ __launch_bounds__(256) void k_past_key(const float* __restrict__ pk,
                                                  short* __restrict__ Kb,
                                                  float* __restrict__ pk_out) {
    int i = (blockIdx.x * 256 + threadIdx.x) * 4;   // over H*P*D = 2M
    int h = i >> 17;                                // P*D = 131072
    f32x4 v = *(const f32x4*)(pk + i);
    int dst = i + (h << 17);                        // [H][T][D], first half
    *(f32x4*)(pk_out + dst) = v;
    unsigned lo = f2bf(v[0]) | ((unsigned)f2bf(v[1]) << 16);
    unsigned hi = f2bf(v[2]) | ((unsigned)f2bf(v[3]) << 16);
    u32x2 p = {lo, hi};
    *(u32x2*)(Kb + dst) = p;
}

// past_value [H][P][D] -> present_v fp32 + Vt bf16 [H][D][T] (transposed)
__global__ __launch_bounds__(256) void k_past_value(const float* __restrict__ pv,
                                                    short* __restrict__ Vt,
                                                    float* __restrict__ pv_out) {
    __shared__ float tile[32][33];
    int h = blockIdx.z;
    int tb = blockIdx.x * 32;   // t
    int db = blockIdx.y * 32;   // d
    int c = threadIdx.x & 31, r0 = threadIdx.x >> 5;
    const float* src = pv + (h << 17);
    float* dst = pv_out + (h << 18);
#pragma unroll
    for (int i = 0; i < 4; ++i) {
        int r = r0 + 8 * i;
        float v = src[(tb + r) * DDIM + db + c];
        tile[r][c] = v;
        dst[(tb + r) * DDIM + db + c] = v;
    }
    __syncthreads();
#pragma unroll
    for (int i = 0; i < 4; ++i) {
        int d = r0 + 8 * i;
        Vt[(h * DDIM + db + d) * TDIM + tb + c] = (short)f2bf(tile[c][d]);
    }
}

// --------------------------- GEMM (m97 structure) --------------------------
// A [M][K] bf16, Bt [N][K] bf16 (pre-transposed). 128x128 tile, BK=32,
// 256 thr = 4 waves (2x2 of 64x64), 16x16x32 MFMA.
// MODE 0: QKV epilogue (q_ws/Kb/Vt/present). MODE 1: proj -> fp32 out + bias.

template <int MODE>
__global__ __launch_bounds__(256) void k_gemm(
    const short* __restrict__ A, const short* __restrict__ Bt,
    const float* __restrict__ bias, int K,
    short* __restrict__ q_ws, short* __restrict__ Kb, short* __restrict__ Vt,
    float* __restrict__ pk, float* __restrict__ pv,
    float* __restrict__ outF, int N) {
    __shared__ short As[128 * 32];
    __shared__ short Bs[128 * 32];
    const int tid = threadIdx.x;
    const int m0 = blockIdx.y * 128, n0 = blockIdx.x * 128;
    const int w = tid >> 6, lane = tid & 63;
    const int wm = w >> 1, wn = w & 1;
    const int l15 = lane & 15, g = lane >> 4;

    f32x4 zero = {0.f, 0.f, 0.f, 0.f};
    f32x4 acc[4][4];
#pragma unroll
    for (int i = 0; i < 4; ++i)
#pragma unroll
        for (int j = 0; j < 4; ++j) acc[i][j] = zero;

    const int arow = tid >> 2;
    const int acol = (tid & 3) << 3;
    const short* Ab  = A  + (m0 + arow) * K + acol;
    const short* Ab2 = A  + (m0 + 64 + arow) * K + acol;
    const short* Bb  = Bt + (n0 + arow) * K + acol;
    const short* Bb2 = Bt + (n0 + 64 + arow) * K + acol;
    short* lA  = &As[tid * 8];
    short* lA2 = &As[2048 + tid * 8];
    short* lB  = &Bs[tid * 8];
    short* lB2 = &Bs[2048 + tid * 8];

    const int aoff = (wm * 64 + l15) * 32 + g * 8;
    const int boff = (wn * 64 + l15) * 32 + g * 8;

    for (int kt = 0; kt < K; kt += 32) {
        async16(Ab + kt, lA);
        async16(Ab2 + kt, lA2);
        async16(Bb + kt, lB);
        async16(Bb2 + kt, lB2);
        __syncthreads();                    // drains vmcnt before use
        bf16x8 af[4], bfr[4];
#pragma unroll
        for (int f = 0; f < 4; ++f) af[f]  = *(const bf16x8*)&As[aoff + f * 512];
#pragma unroll
        for (int f = 0; f < 4; ++f) bfr[f] = *(const bf16x8*)&Bs[boff + f * 512];
#pragma unroll
        for (int i = 0; i < 4; ++i)
#pragma unroll
            for (int j = 0; j < 4; ++j)
                acc[i][j] = __builtin_amdgcn_mfma_f32_16x16x32_bf16(
                    af[i], bfr[j], acc[i][j], 0, 0, 0);
        __syncthreads();
    }

    // Epilogue: C[row][col], row = m0+wm*64+i*16+4g+r, col = n0+wn*64+j*16+l15
    if (MODE == 1) {
#pragma unroll
        for (int j = 0; j < 4; ++j) {
            int ncol = n0 + wn * 64 + j * 16 + l15;
            float b = bias[ncol];
#pragma unroll
            for (int i = 0; i < 4; ++i) {
                int mb = m0 + wm * 64 + i * 16 + g * 4;
#pragma unroll
                for (int r = 0; r < 4; ++r)
                    outF[(mb + r) * N + ncol] = acc[i][j][r] + b;
            }
        }
    } else {
        const int sec = n0 >> 10;   // 0=q 1=k 2=v (uniform per block)
#pragma unroll
        for (int j = 0; j < 4; ++j) {
            int ncol = n0 + wn * 64 + j * 16 + l15;
            float b = bias[ncol];
            int h = (ncol >> 6) & 15;
            int d = ncol & 63;
#pragma unroll
            for (int i = 0; i < 4; ++i) {
                int mb = m0 + wm * 64 + i * 16 + g * 4;
#pragma unroll
                for (int r = 0; r < 4; ++r) {
                    int s = mb + r;
                    float val = acc[i][j][r] + b;
                    if (sec == 0) {
                        q_ws[(h * SDIM + s) * DDIM + d] = (short)f2bf(val * 0.125f);
                    } else if (sec == 1) {
                        int idx = (h * TDIM + PDIM + s) * DDIM + d;
                        pk[idx] = val;
                        Kb[idx] = (short)f2bf(val);
                    } else {
                        pv[(h * TDIM + PDIM + s) * DDIM + d] = val;
                        Vt[(h * DDIM + d) * TDIM + PDIM + s] = (short)f2bf(val);
                    }
                }
            }
        }
    }
}

// --------------------------- flash attention -------------------------------
// Block: h = bid&15 (XCD n hosts heads n, n+8 -> 4MB K+V = one L2).
// qt remapped for load balance (ntiles = 33+qt): adjacent blocks pair i, 31-i.
// 4 waves x 16 q-rows, 64-key tiles. K and V tiles staged in LDS via
// global_load_lds (16B), double-buffered; T2 XOR swizzle (byte^=((row&7)<<4))
// applied by pre-swizzling the GLOBAL source (rule #21), un-swizzled on the
// ds_read side -> bank-optimal (8 words/bank = wave64 b128 floor).
// Swapped QK^T: S^T = mfma(K, Q); per-lane softmax stats via 2 shfl_xor.
__global__ __launch_bounds__(256) void k_attn(const short* __restrict__ q_ws,
                                              const short* __restrict__ Kb,
                                              const short* __restrict__ Vt,
                                              short* __restrict__ aout) {
    __shared__ short Ks[2][64 * 64];   // [buf][row=key][d]  (swizzled layout)
    __shared__ short Vs[2][64 * 64];   // [buf][row=d][t]    (swizzled layout)
    __shared__ short Pl[4][16][72];    // per wave: [q 16][key 64], +8 pad
    const int tid = threadIdx.x;
    const int w = tid >> 6, lane = tid & 63;
    const int l15 = lane & 15, g = lane >> 4;
    const int h = blockIdx.x & 15;
    const int j = blockIdx.x >> 4;
    const int qt = (j & 1) ? (31 - (j >> 1)) : (j >> 1);   // balance pairing
    const int q = qt * 64 + w * 16 + l15;   // this lane's q row

    const short* qb = q_ws + (h * SDIM + q) * DDIM;   // pre-scaled by 0.125
    bf16x8 bq0 = *(const bf16x8*)(qb + g * 8);
    bf16x8 bq1 = *(const bf16x8*)(qb + 32 + g * 8);

    const short* Kh = Kb + h * TDIM * DDIM;
    const short* Vh = Vt + h * DDIM * TDIM;

    f32x4 zero = {0.f, 0.f, 0.f, 0.f};
    f32x4 o[4] = {zero, zero, zero, zero};
    float m_run = -1e30f, l_run = 0.f;
    const int ntiles = 33 + qt;             // exactly covers keys <= P+q0+63
    short* myP = &Pl[w][0][0];
    const int r7 = (l15 & 7) << 4;          // read-side XOR (bits 4..6)

    // stage one 64-key K tile + V tile into buffer `buf`; wave w covers
    // bytes [w*1024 + i*4096 .. +1024) of each 8KB tile; source pre-swizzled.
    auto stage = [&](int buf, int t) {
        const int t0 = t * 64;
        const char* Kg = (const char*)(Kh + t0 * DDIM);   // contiguous 8KB
        const char* Vg = (const char*)(Vh + t0);          // rows of 128B, stride 8192B
#pragma unroll
        for (int i = 0; i < 2; ++i) {
            int b = w * 1024 + i * 4096 + (lane << 4);    // dest byte in tile
            int sb = b ^ (((b >> 7) & 7) << 4);           // swizzled source byte
            async16(Kg + sb, (char*)&Ks[buf][0] + w * 1024 + i * 4096);
            int vrow = b >> 7;
            int vcol = (b & 127) ^ ((vrow & 7) << 4);
            async16(Vg + vrow * (TDIM * 2) + vcol,
                    (char*)&Vs[buf][0] + w * 1024 + i * 4096);
        }
    };

    int cur = 0;
    stage(0, 0);
    __syncthreads();                         // drains vmcnt + lgkm

    for (int t = 0; t < ntiles; ++t) {
        const int t0 = t * 64;
        if (t + 1 < ntiles) stage(cur ^ 1, t + 1);   // prefetch next tile

        const char* Kc = (const char*)&Ks[cur][0];
        const char* Vc = (const char*)&Vs[cur][0];

        f32x4 sc[4];
#pragma unroll
        for (int kb = 0; kb < 4; ++kb) {    // S^T[key][q]
            const char* kr = Kc + (kb * 16 + l15) * 128;
            bf16x8 ak0 = *(const bf16x8*)(kr + ((g * 16) ^ r7));
            bf16x8 ak1 = *(const bf16x8*)(kr + ((64 + g * 16) ^ r7));
            f32x4 c = zero;
            c = __builtin_amdgcn_mfma_f32_16x16x32_bf16(ak0, bq0, c, 0, 0, 0);
            c = __builtin_amdgcn_mfma_f32_16x16x32_bf16(ak1, bq1, c, 0, 0, 0);
            sc[kb] = c;
        }
        if (t == ntiles - 1) {              // causal mask, last tile only
#pragma unroll
            for (int kb = 0; kb < 4; ++kb)
#pragma unroll
                for (int i = 0; i < 4; ++i)
                    if (t0 + kb * 16 + g * 4 + i > PDIM + q) sc[kb][i] = -1e30f;
        }
        float tmax = sc[0][0];
#pragma unroll
        for (int kb = 0; kb < 4; ++kb)
#pragma unroll
            for (int i = 0; i < 4; ++i) tmax = fmaxf(tmax, sc[kb][i]);
        tmax = fmaxf(tmax, __shfl_xor(tmax, 16));
        tmax = fmaxf(tmax, __shfl_xor(tmax, 32));
        float m_new = fmaxf(m_run, tmax);
        float scale = __expf(m_run - m_new);
        float psum = 0.f;
        unsigned pw[8];
#pragma unroll
        for (int kb = 0; kb < 4; ++kb) {
            float p0 = __expf(sc[kb][0] - m_new);
            float p1 = __expf(sc[kb][1] - m_new);
            float p2 = __expf(sc[kb][2] - m_new);
            float p3 = __expf(sc[kb][3] - m_new);
            psum += (p0 + p1) + (p2 + p3);
            asm("v_cvt_pk_bf16_f32 %0, %1, %2"
                : "=v"(pw[2 * kb]) : "v"(p0), "v"(p1));
            asm("v_cvt_pk_bf16_f32 %0, %1, %2"
                : "=v"(pw[2 * kb + 1]) : "v"(p2), "v"(p3));
        }
        psum += __shfl_xor(psum, 16);
        psum += __shfl_xor(psum, 32);
        l_run = l_run * scale + psum;
        m_run = m_new;
#pragma unroll
        for (int d = 0; d < 4; ++d) o[d] *= scale;
#pragma unroll
        for (int kb = 0; kb < 4; ++kb) {    // P[q][key], 8B per lane per kb
            u32x2 pk2 = {pw[2 * kb], pw[2 * kb + 1]};
            *(u32x2*)(myP + l15 * 72 + kb * 16 + g * 4) = pk2;
        }
        asm volatile("s_waitcnt lgkmcnt(0)" ::: "memory");
        __builtin_amdgcn_sched_barrier(0);
        bf16x8 bp0 = *(const bf16x8*)(myP + l15 * 72 + g * 8);
        bf16x8 bp1 = *(const bf16x8*)(myP + l15 * 72 + 32 + g * 8);
#pragma unroll
        for (int d = 0; d < 4; ++d) {       // O^T[d][q] += V^T . P^T
            const char* vr = Vc + (d * 16 + l15) * 128;
            bf16x8 av0 = *(const bf16x8*)(vr + ((g * 16) ^ r7));
            bf16x8 av1 = *(const bf16x8*)(vr + ((64 + g * 16) ^ r7));
            o[d] = __builtin_amdgcn_mfma_f32_16x16x32_bf16(av0, bp0, o[d], 0, 0, 0);
            o[d] = __builtin_amdgcn_mfma_f32_16x16x32_bf16(av1, bp1, o[d], 0, 0, 0);
        }
        __syncthreads();                    // drains vmcnt (prefetch) + compute
        cur ^= 1;
    }
    float inv = 1.0f / l_run;
#pragma unroll
    for (int d = 0; d < 4; ++d) {
        unsigned lo = f2bf(o[d][0] * inv) | ((unsigned)f2bf(o[d][1] * inv) << 16);
        unsigned hi = f2bf(o[d][2] * inv) | ((unsigned)f2bf(o[d][3] * inv) << 16);
        u32x2 pk2 = {lo, hi};
        *(u32x2*)(aout + q * EDIM + h * DDIM + d * 16 + g * 4) = pk2;
    }
}

// --------------------------- launch ----------------------------------------

extern "C" void kernel_launch(void* const* d_in, const int* in_sizes, int n_in,
                              void* d_out, int out_size, void* d_ws, size_t ws_size,
                              hipStream_t stream) {
    const float* x          = (const float*)d_in[0];
    const float* past_key   = (const float*)d_in[1];
    const float* past_value = (const float*)d_in[2];
    // d_in[3] = mask: recomputed analytically (k <= q + P)
    const float* c_attn_w   = (const float*)d_in[4];
    const float* c_attn_b   = (const float*)d_in[5];
    const float* c_proj_w   = (const float*)d_in[6];
    const float* c_proj_b   = (const float*)d_in[7];

    float* out_a  = (float*)d_out;
    float* pk_out = out_a + (size_t)SDIM * EDIM;           // present[0]
    float* pv_out = pk_out + (size_t)HNUM * TDIM * DDIM;   // present[1]

    char* ws = (char*)d_ws;
    short* xb     = (short*)(ws);                //  4 MB
    short* wqkvt  = (short*)(ws + (4u  << 20));  //  6 MB  [3E][E]
    short* wprojt = (short*)(ws + (10u << 20));  //  2 MB  [E][E]
    short* q_ws   = (short*)(ws + (12u << 20));  //  4 MB  [H][S][D] *0.125
    short* Kb     = (short*)(ws + (16u << 20));  //  8 MB  [H][T][D]
    short* Vt     = (short*)(ws + (24u << 20));  //  8 MB  [H][D][T]
    short* aout   = (short*)(ws + (32u << 20));  //  4 MB  [S][E]

    k_cvt_x<<<2048, 256, 0, stream>>>(x, xb);
    k_tr_cvt<<<dim3(96, 32), 256, 0, stream>>>(c_attn_w, wqkvt, EDIM, 3 * EDIM);
    k_tr_cvt<<<dim3(32, 32), 256, 0, stream>>>(c_proj_w, wprojt, EDIM, EDIM);
    k_past_key<<<2048, 256, 0, stream>>>(past_key, Kb, pk_out);
    k_past_value<<<dim3(64, 2, 16), 256, 0, stream>>>(past_value, Vt, pv_out);

    k_gemm<0><<<dim3(24, 16), 256, 0, stream>>>(
        xb, wqkvt, c_attn_b, EDIM, q_ws, Kb, Vt, pk_out, pv_out,
        (float*)nullptr, 3 * EDIM);

    k_attn<<<512, 256, 0, stream>>>(q_ws, Kb, Vt, aout);

    k_gemm<1><<<dim3(8, 16), 256, 0, stream>>>(
        aout, wprojt, c_proj_b, EDIM,
        (short*)nullptr, (short*)nullptr, (short*)nullptr,
        (float*)nullptr, (float*)nullptr, out_a, EDIM);
}